// Round 1
// baseline (151.689 us; speedup 1.0000x reference)
//
#include <hip/hip_runtime.h>
#include <hip/hip_bf16.h>

// Problem: KAN layer. out = einsum('bik,jik->bj', rbf(x), W) + silu(x)@Wb^T, then LN.
// B=4096, I=512, K=16, J=512.  => GEMM [4096 x 8704] * [512 x 8704]^T in bf16 MFMA.
//
// d_ws layout (needs ~92.5 MB):
//   A  bf16 [4096][8704]  @ 0          (71,303,168 B)   A = [basis | silu(x)]
//   Bm bf16 [512][8704]   @ 71303168   ( 8,912,896 B)   Bm = [W | Wb]
//   Cp f32  [4][4096][512]@ 80216064   (33,554,432 B)   split-K partials
// total 113,770,496 B

typedef __bf16 bf16x8 __attribute__((ext_vector_type(8)));
typedef __bf16 bf16x4 __attribute__((ext_vector_type(4)));
typedef float  f32x4  __attribute__((ext_vector_type(4)));

#define KT 8704            // total K = 512*16 + 512
#define SPLITS 4
#define KS (KT / SPLITS)   // 2176, = 68 iters of BK=32
#define CP_STRIDE (4096 * 512)

__device__ __forceinline__ void gll16(const __bf16* g, __bf16* l) {
    __builtin_amdgcn_global_load_lds(
        (const __attribute__((address_space(1))) void*)g,
        (__attribute__((address_space(3))) void*)l, 16, 0, 0);
}

// ---- kernel 1: A = [rbf basis | silu(x)] in bf16 -------------------------
// centers linspace(-2,2,16), h = 4/15  =>  z_k = x/h - c_k/h = 3.75x + 7.5 - k
__global__ void prep_A(const float* __restrict__ x, __bf16* __restrict__ A) {
    int t = blockIdx.x * 256 + threadIdx.x;      // 0 .. 4096*512
    int b = t >> 9;
    int i = t & 511;
    float xv = x[t];
    float zb = 3.75f * xv + 7.5f;
    bf16x8 lo, hi;
#pragma unroll
    for (int k = 0; k < 8; ++k) { float z = zb - (float)k;     lo[k]   = (__bf16)__expf(-z * z); }
#pragma unroll
    for (int k = 8; k < 16; ++k){ float z = zb - (float)k;     hi[k-8] = (__bf16)__expf(-z * z); }
    size_t base = (size_t)b * KT + (size_t)i * 16;
    *(bf16x8*)(A + base)     = lo;
    *(bf16x8*)(A + base + 8) = hi;
    float s = xv / (1.0f + __expf(-xv));         // silu
    A[(size_t)b * KT + 8192 + i] = (__bf16)s;
}

// ---- kernel 2: Bm = [W | Wb] cast to bf16 --------------------------------
__global__ void prep_B(const float* __restrict__ W, const float* __restrict__ Wb,
                       __bf16* __restrict__ B) {
    int t = blockIdx.x * 256 + threadIdx.x;      // 0 .. 512*2176
    int j  = t / 2176;
    int c  = (t - j * 2176) * 4;
    float4 v;
    if (c < 8192) v = *(const float4*)&W[(size_t)j * 8192 + c];
    else          v = *(const float4*)&Wb[(size_t)j * 512 + (c - 8192)];
    bf16x4 o;
    o[0] = (__bf16)v.x; o[1] = (__bf16)v.y; o[2] = (__bf16)v.z; o[3] = (__bf16)v.w;
    *(bf16x4*)&B[(size_t)j * KT + c] = o;
}

// ---- kernel 3: C_partial[z] = A[128-tile] * B[128-tile]^T over K-split ----
// m97 structure: BM=BN=128, BK=32, 4 waves, global_load_lds w16, 16x16x32 MFMA.
__global__ __launch_bounds__(256, 2) void gemm_bt(const __bf16* __restrict__ A,
                                                  const __bf16* __restrict__ B,
                                                  float* __restrict__ Cp) {
    __shared__ __attribute__((aligned(16))) __bf16 As[128 * 32];
    __shared__ __attribute__((aligned(16))) __bf16 Bs[128 * 32];

    const int tid  = threadIdx.x;
    const int wave = tid >> 6, lane = tid & 63;
    const int q    = lane >> 4, r16 = lane & 15;
    const int m0 = blockIdx.x * 128, n0 = blockIdx.y * 128, k0 = blockIdx.z * KS;
    const int wm = wave & 1, wn = wave >> 1;

    // staging: 512 chunks of 16B per tile; thread handles chunk tid and tid+256
    const __bf16* gA0 = A + (size_t)(m0 + (tid >> 2)) * KT + k0 + (tid & 3) * 8;
    const __bf16* gA1 = gA0 + (size_t)64 * KT;
    const __bf16* gB0 = B + (size_t)(n0 + (tid >> 2)) * KT + k0 + (tid & 3) * 8;
    const __bf16* gB1 = gB0 + (size_t)64 * KT;
    __bf16* lA0 = &As[tid * 8];
    __bf16* lA1 = &As[(tid + 256) * 8];
    __bf16* lB0 = &Bs[tid * 8];
    __bf16* lB1 = &Bs[(tid + 256) * 8];

    f32x4 acc[4][4] = {};

    const __bf16* Aw = &As[(wm * 64 + r16) * 32 + q * 8];
    const __bf16* Bw = &Bs[(wn * 64 + r16) * 32 + q * 8];

    for (int it = 0; it < KS / 32; ++it) {
        const int ko = it * 32;
        gll16(gA0 + ko, lA0);
        gll16(gA1 + ko, lA1);
        gll16(gB0 + ko, lB0);
        gll16(gB1 + ko, lB1);
        __syncthreads();

        bf16x8 af[4], bg[4];
#pragma unroll
        for (int mi = 0; mi < 4; ++mi) af[mi] = *(const bf16x8*)(Aw + mi * 512);
#pragma unroll
        for (int ni = 0; ni < 4; ++ni) bg[ni] = *(const bf16x8*)(Bw + ni * 512);
#pragma unroll
        for (int mi = 0; mi < 4; ++mi)
#pragma unroll
            for (int ni = 0; ni < 4; ++ni)
                acc[mi][ni] = __builtin_amdgcn_mfma_f32_16x16x32_bf16(
                    af[mi], bg[ni], acc[mi][ni], 0, 0, 0);
        __syncthreads();
    }

    // epilogue: C/D layout col=lane&15, row=(lane>>4)*4+reg  [guide §3, m89-verified]
    float* Cb = Cp + (size_t)blockIdx.z * CP_STRIDE;
#pragma unroll
    for (int mi = 0; mi < 4; ++mi) {
        const int row = m0 + wm * 64 + mi * 16 + q * 4;
#pragma unroll
        for (int ni = 0; ni < 4; ++ni) {
            const int col = n0 + wn * 64 + ni * 16 + r16;
#pragma unroll
            for (int r = 0; r < 4; ++r)
                Cb[(size_t)(row + r) * 512 + col] = acc[mi][ni][r];
        }
    }
}

// ---- kernel 4: sum split-K partials + LayerNorm, one wave per row ---------
__global__ void ln_kernel(const float* __restrict__ Cp, const float* __restrict__ gamma,
                          const float* __restrict__ beta, float* __restrict__ out) {
    const int tid  = threadIdx.x;
    const int wave = tid >> 6, lane = tid & 63;
    const int row  = blockIdx.x * 4 + wave;
    const float* p = Cp + (size_t)row * 512;
    float v[8], s = 0.f, s2 = 0.f;
#pragma unroll
    for (int u = 0; u < 8; ++u) {
        const int col = lane + u * 64;
        float a = p[col] + p[col + CP_STRIDE] + p[col + 2 * CP_STRIDE] + p[col + 3 * CP_STRIDE];
        v[u] = a; s += a; s2 += a * a;
    }
#pragma unroll
    for (int m = 32; m >= 1; m >>= 1) {
        s  += __shfl_xor(s, m);
        s2 += __shfl_xor(s2, m);
    }
    const float mean = s * (1.0f / 512.0f);
    const float var  = s2 * (1.0f / 512.0f) - mean * mean;
    const float rs   = rsqrtf(var + 1e-5f);
#pragma unroll
    for (int u = 0; u < 8; ++u) {
        const int col = lane + u * 64;
        out[(size_t)row * 512 + col] = (v[u] - mean) * rs * gamma[col] + beta[col];
    }
}

extern "C" void kernel_launch(void* const* d_in, const int* in_sizes, int n_in,
                              void* d_out, int out_size, void* d_ws, size_t ws_size,
                              hipStream_t stream) {
    const float* x     = (const float*)d_in[0];
    const float* W     = (const float*)d_in[1];
    const float* Wb    = (const float*)d_in[2];
    const float* gamma = (const float*)d_in[3];
    const float* beta  = (const float*)d_in[4];
    float* out = (float*)d_out;

    char* ws = (char*)d_ws;
    __bf16* A  = (__bf16*)ws;                                   // 71,303,168 B
    __bf16* Bm = (__bf16*)(ws + 71303168);                      //  8,912,896 B
    float*  Cp = (float*)(ws + 71303168 + 8912896);             // 33,554,432 B

    prep_A<<<8192, 256, 0, stream>>>(x, A);
    prep_B<<<4352, 256, 0, stream>>>(W, Wb, Bm);
    dim3 g(32, 4, SPLITS);
    gemm_bt<<<g, 256, 0, stream>>>(A, Bm, Cp);
    ln_kernel<<<1024, 256, 0, stream>>>(Cp, gamma, beta, out);
}

// Round 2
// 148.920 us; speedup vs baseline: 1.0186x; 1.0186x over previous
//
#include <hip/hip_runtime.h>
#include <hip/hip_bf16.h>

// KAN layer: out = einsum('bik,jik->bj', rbf(x), W) + silu(x)@Wb^T, then LN.
// GEMM view: C[4096,512] = A[4096,8704] * B[512,8704]^T in bf16 MFMA.
//
// d_ws layout (113,770,496 B total — same footprint as the passing R1):
//   A  bf16 [4096][8704]     @ 0          (71,303,168 B)  A = [basis | silu(x)]
//   Bm bf16 [512][8704]      @ 71303168   ( 8,912,896 B)  Bm = [W | Wb]
//   Cp bf16 [8][4096][512]   @ 80216064   (33,554,432 B)  split-K partials (bf16)

typedef __bf16 bf16x8 __attribute__((ext_vector_type(8)));
typedef __bf16 bf16x4 __attribute__((ext_vector_type(4)));
typedef float  f32x4  __attribute__((ext_vector_type(4)));

#define KT 8704            // total K = 512*16 + 512
#define SPLITS 8
#define KS (KT / SPLITS)   // 1088 = 34 iters of BK=32
#define CPE (4096 * 512)   // elements per partial

__device__ __forceinline__ void gll16(const __bf16* g, __bf16* l) {
    __builtin_amdgcn_global_load_lds(
        (const __attribute__((address_space(1))) void*)g,
        (__attribute__((address_space(3))) void*)l, 16, 0, 0);
}

// ---- kernel 1: A = [rbf basis | silu(x)], Bm = [W | Wb], both bf16 --------
// centers linspace(-2,2,16), h = 4/15 => z_k = 3.75x + 7.5 - k
__global__ void prep_AB(const float* __restrict__ x, const float* __restrict__ W,
                        const float* __restrict__ Wb, __bf16* __restrict__ A,
                        __bf16* __restrict__ B) {
    if (blockIdx.x < 8192) {                     // A-part: 1 thread per x elem
        int t = blockIdx.x * 256 + threadIdx.x;  // 0 .. 4096*512
        int b = t >> 9;
        int i = t & 511;
        float xv = x[t];
        float zb = 3.75f * xv + 7.5f;
        bf16x8 lo, hi;
#pragma unroll
        for (int k = 0; k < 8; ++k) { float z = zb - (float)k; lo[k]   = (__bf16)__expf(-z * z); }
#pragma unroll
        for (int k = 8; k < 16; ++k){ float z = zb - (float)k; hi[k-8] = (__bf16)__expf(-z * z); }
        size_t base = (size_t)b * KT + (size_t)i * 16;
        *(bf16x8*)(A + base)     = lo;
        *(bf16x8*)(A + base + 8) = hi;
        float s = xv / (1.0f + __expf(-xv));     // silu
        A[(size_t)b * KT + 8192 + i] = (__bf16)s;
    } else {                                     // B-part: cast W|Wb, 4 elems/thread
        int t = (blockIdx.x - 8192) * 256 + threadIdx.x;  // 0 .. 512*2176
        int j = t / 2176;
        int c = (t - j * 2176) * 4;
        float4 v;
        if (c < 8192) v = *(const float4*)&W[(size_t)j * 8192 + c];
        else          v = *(const float4*)&Wb[(size_t)j * 512 + (c - 8192)];
        bf16x4 o;
        o[0] = (__bf16)v.x; o[1] = (__bf16)v.y; o[2] = (__bf16)v.z; o[3] = (__bf16)v.w;
        *(bf16x4*)&B[(size_t)j * KT + c] = o;
    }
}

// ---- kernel 2: split-K GEMM, 128x128 tile, BK=32, swizzled LDS ------------
// LDS chunk layout: 16B chunk for (row, qk) lives at chunk row*4 + (qk ^ ((row>>1)&3)).
// Staging permutes the GLOBAL source per lane (LDS side of global_load_lds is
// lane-linear and can't scatter); read side uses q ^ ((r16>>1)&3) -> 8
// consecutive lanes hit 8 distinct bank quads -> conflict-free ds_read_b128.
__global__ __launch_bounds__(256, 4) void gemm_bt(const __bf16* __restrict__ A,
                                                  const __bf16* __restrict__ B,
                                                  __bf16* __restrict__ Cp) {
    __shared__ __attribute__((aligned(16))) __bf16 As[128 * 32];
    __shared__ __attribute__((aligned(16))) __bf16 Bs[128 * 32];

    const int tid  = threadIdx.x;
    const int wave = tid >> 6, lane = tid & 63;
    const int q    = lane >> 4, r16 = lane & 15;
    const int m0 = blockIdx.x * 128, n0 = blockIdx.y * 128, k0 = blockIdx.z * KS;
    const int wm = wave & 1, wn = wave >> 1;

    // staging source (swizzled): chunk c holds global (row=c>>2, qk=(c&3)^((row>>1)&3))
    const int row0 = tid >> 2, qk0 = (tid & 3) ^ ((row0 >> 1) & 3);
    const int row1 = row0 + 64, qk1 = (tid & 3) ^ ((row1 >> 1) & 3);
    const __bf16* gA0 = A + (size_t)(m0 + row0) * KT + k0 + qk0 * 8;
    const __bf16* gA1 = A + (size_t)(m0 + row1) * KT + k0 + qk1 * 8;
    const __bf16* gB0 = B + (size_t)(n0 + row0) * KT + k0 + qk0 * 8;
    const __bf16* gB1 = B + (size_t)(n0 + row1) * KT + k0 + qk1 * 8;
    __bf16* lA0 = &As[tid * 8];
    __bf16* lA1 = &As[(tid + 256) * 8];
    __bf16* lB0 = &Bs[tid * 8];
    __bf16* lB1 = &Bs[(tid + 256) * 8];

    f32x4 acc[4][4] = {};

    const int qa = q ^ ((r16 >> 1) & 3);         // de-swizzle for reads
    const __bf16* Aw = &As[(wm * 64 + r16) * 32 + qa * 8];
    const __bf16* Bw = &Bs[(wn * 64 + r16) * 32 + qa * 8];

    for (int it = 0; it < KS / 32; ++it) {
        const int ko = it * 32;
        gll16(gA0 + ko, lA0);
        gll16(gA1 + ko, lA1);
        gll16(gB0 + ko, lB0);
        gll16(gB1 + ko, lB1);
        __syncthreads();

        bf16x8 af[4], bg[4];
#pragma unroll
        for (int mi = 0; mi < 4; ++mi) af[mi] = *(const bf16x8*)(Aw + mi * 512);
#pragma unroll
        for (int ni = 0; ni < 4; ++ni) bg[ni] = *(const bf16x8*)(Bw + ni * 512);
#pragma unroll
        for (int mi = 0; mi < 4; ++mi)
#pragma unroll
            for (int ni = 0; ni < 4; ++ni)
                acc[mi][ni] = __builtin_amdgcn_mfma_f32_16x16x32_bf16(
                    af[mi], bg[ni], acc[mi][ni], 0, 0, 0);
        __syncthreads();
    }

    // epilogue: C/D layout col=lane&15, row=(lane>>4)*4+reg; bf16 partials
    __bf16* Cb = Cp + (size_t)blockIdx.z * CPE;
#pragma unroll
    for (int mi = 0; mi < 4; ++mi) {
        const int row = m0 + wm * 64 + mi * 16 + q * 4;
#pragma unroll
        for (int ni = 0; ni < 4; ++ni) {
            const int col = n0 + wn * 64 + ni * 16 + r16;
#pragma unroll
            for (int r = 0; r < 4; ++r)
                Cb[(size_t)(row + r) * 512 + col] = (__bf16)acc[mi][ni][r];
        }
    }
}

// ---- kernel 3: sum 8 bf16 partials + LayerNorm, one wave per row ----------
__global__ void ln_kernel(const __bf16* __restrict__ Cp, const float* __restrict__ gamma,
                          const float* __restrict__ beta, float* __restrict__ out) {
    const int tid  = threadIdx.x;
    const int wave = tid >> 6, lane = tid & 63;
    const int row  = blockIdx.x * 4 + wave;
    const size_t base = (size_t)row * 512 + lane * 8;   // 8 contiguous cols/lane

    float v[8] = {};
    float s = 0.f, s2 = 0.f;
#pragma unroll
    for (int z = 0; z < SPLITS; ++z) {
        bf16x8 p = *(const bf16x8*)(Cp + (size_t)z * CPE + base);
#pragma unroll
        for (int j = 0; j < 8; ++j) v[j] += (float)p[j];
    }
#pragma unroll
    for (int j = 0; j < 8; ++j) { s += v[j]; s2 += v[j] * v[j]; }
#pragma unroll
    for (int m = 32; m >= 1; m >>= 1) {
        s  += __shfl_xor(s, m);
        s2 += __shfl_xor(s2, m);
    }
    const float mean = s * (1.0f / 512.0f);
    const float var  = s2 * (1.0f / 512.0f) - mean * mean;
    const float rs   = rsqrtf(var + 1e-5f);
    float4 o0, o1;
    const float4 g0 = *(const float4*)&gamma[lane * 8];
    const float4 g1 = *(const float4*)&gamma[lane * 8 + 4];
    const float4 b0 = *(const float4*)&beta[lane * 8];
    const float4 b1 = *(const float4*)&beta[lane * 8 + 4];
    o0.x = (v[0] - mean) * rs * g0.x + b0.x;
    o0.y = (v[1] - mean) * rs * g0.y + b0.y;
    o0.z = (v[2] - mean) * rs * g0.z + b0.z;
    o0.w = (v[3] - mean) * rs * g0.w + b0.w;
    o1.x = (v[4] - mean) * rs * g1.x + b1.x;
    o1.y = (v[5] - mean) * rs * g1.y + b1.y;
    o1.z = (v[6] - mean) * rs * g1.z + b1.z;
    o1.w = (v[7] - mean) * rs * g1.w + b1.w;
    *(float4*)&out[base]     = o0;
    *(float4*)&out[base + 4] = o1;
}

extern "C" void kernel_launch(void* const* d_in, const int* in_sizes, int n_in,
                              void* d_out, int out_size, void* d_ws, size_t ws_size,
                              hipStream_t stream) {
    const float* x     = (const float*)d_in[0];
    const float* W     = (const float*)d_in[1];
    const float* Wb    = (const float*)d_in[2];
    const float* gamma = (const float*)d_in[3];
    const float* beta  = (const float*)d_in[4];
    float* out = (float*)d_out;

    char* ws = (char*)d_ws;
    __bf16* A  = (__bf16*)ws;                        // 71,303,168 B
    __bf16* Bm = (__bf16*)(ws + 71303168);           //  8,912,896 B
    __bf16* Cp = (__bf16*)(ws + 80216064);           // 33,554,432 B

    prep_AB<<<8192 + 4352, 256, 0, stream>>>(x, W, Wb, A, Bm);
    dim3 g(32, 4, SPLITS);
    gemm_bt<<<g, 256, 0, stream>>>(A, Bm, Cp);
    ln_kernel<<<1024, 256, 0, stream>>>(Cp, gamma, beta, out);
}

// Round 3
// 143.545 us; speedup vs baseline: 1.0567x; 1.0374x over previous
//
#include <hip/hip_runtime.h>
#include <hip/hip_bf16.h>

// KAN layer: out = einsum('bik,jik->bj', rbf(x), W) + silu(x)@Wb^T, then LN.
// GEMM view: C[4096,512] = A[4096,8704] * B[512,8704]^T in bf16 MFMA.
//
// d_ws layout (113,770,496 B total):
//   A  bf16 [4096][8704]     @ 0          (71,303,168 B)  A = [basis | silu(x)]
//   Bm bf16 [512][8704]      @ 71303168   ( 8,912,896 B)  Bm = [W | Wb]
//   Cp bf16 [8][4096][512]   @ 80216064   (33,554,432 B)  split-K partials (bf16)

typedef __bf16 bf16x8 __attribute__((ext_vector_type(8)));
typedef __bf16 bf16x4 __attribute__((ext_vector_type(4)));
typedef float  f32x4  __attribute__((ext_vector_type(4)));

#define KT 8704            // total K = 512*16 + 512
#define SPLITS 8
#define KS (KT / SPLITS)   // 1088 = 34 iters of BK=32
#define NIT (KS / 32)
#define CPE (4096 * 512)   // elements per partial
#define LBUF (128 * 32)    // one LDS tile buffer, elements

__device__ __forceinline__ void gll16(const __bf16* g, __bf16* l) {
    __builtin_amdgcn_global_load_lds(
        (const __attribute__((address_space(1))) void*)g,
        (__attribute__((address_space(3))) void*)l, 16, 0, 0);
}

// ---- kernel 1: A = [rbf basis | silu(x)], Bm = [W | Wb], both bf16 --------
// centers linspace(-2,2,16), h = 4/15 => z_k = 3.75x + 7.5 - k
__global__ void prep_AB(const float* __restrict__ x, const float* __restrict__ W,
                        const float* __restrict__ Wb, __bf16* __restrict__ A,
                        __bf16* __restrict__ B) {
    if (blockIdx.x < 8192) {                     // A-part: 1 thread per x elem
        int t = blockIdx.x * 256 + threadIdx.x;  // 0 .. 4096*512
        int b = t >> 9;
        int i = t & 511;
        float xv = x[t];
        float zb = 3.75f * xv + 7.5f;
        bf16x8 lo, hi;
#pragma unroll
        for (int k = 0; k < 8; ++k) { float z = zb - (float)k; lo[k]   = (__bf16)__expf(-z * z); }
#pragma unroll
        for (int k = 8; k < 16; ++k){ float z = zb - (float)k; hi[k-8] = (__bf16)__expf(-z * z); }
        size_t base = (size_t)b * KT + (size_t)i * 16;
        *(bf16x8*)(A + base)     = lo;
        *(bf16x8*)(A + base + 8) = hi;
        float s = xv / (1.0f + __expf(-xv));     // silu
        A[(size_t)b * KT + 8192 + i] = (__bf16)s;
    } else {                                     // B-part: cast W|Wb, 4 elems/thread
        int t = (blockIdx.x - 8192) * 256 + threadIdx.x;  // 0 .. 512*2176
        int j = t / 2176;
        int c = (t - j * 2176) * 4;
        float4 v;
        if (c < 8192) v = *(const float4*)&W[(size_t)j * 8192 + c];
        else          v = *(const float4*)&Wb[(size_t)j * 512 + (c - 8192)];
        bf16x4 o;
        o[0] = (__bf16)v.x; o[1] = (__bf16)v.y; o[2] = (__bf16)v.z; o[3] = (__bf16)v.w;
        *(bf16x4*)&B[(size_t)j * KT + c] = o;
    }
}

// ---- kernel 2: split-K GEMM, 128x128, BK=32, swizzled + double-buffered ---
// LDS chunk swizzle: 16B chunk (row, qk) lives at chunk row*4 + (qk ^ ((row>>1)&3)).
// Double-buffer with ONE barrier per iter, placed AFTER compute: the compiler's
// vmcnt(0) drain at __syncthreads then overlaps the just-issued DMA with the
// ~350 cyc of ds_read+MFMA — hides the L2/LLC staging latency that made R2's
// 2-barrier loop convoy (MfmaUtil 26%, LDS pipe ~38% busy).
__global__ __launch_bounds__(256, 4) void gemm_bt(const __bf16* __restrict__ A,
                                                  const __bf16* __restrict__ B,
                                                  __bf16* __restrict__ Cp) {
    __shared__ __attribute__((aligned(16))) __bf16 As[2 * LBUF];
    __shared__ __attribute__((aligned(16))) __bf16 Bs[2 * LBUF];

    const int tid  = threadIdx.x;
    const int wave = tid >> 6, lane = tid & 63;
    const int q    = lane >> 4, r16 = lane & 15;
    const int m0 = blockIdx.x * 128, n0 = blockIdx.y * 128, k0 = blockIdx.z * KS;
    const int wm = wave & 1, wn = wave >> 1;

    // staging source (swizzled): chunk c holds global (row=c>>2, qk=(c&3)^((row>>1)&3))
    const int row0 = tid >> 2, qk0 = (tid & 3) ^ ((row0 >> 1) & 3);
    const int row1 = row0 + 64, qk1 = (tid & 3) ^ ((row1 >> 1) & 3);
    const __bf16* gA0 = A + (size_t)(m0 + row0) * KT + k0 + qk0 * 8;
    const __bf16* gA1 = A + (size_t)(m0 + row1) * KT + k0 + qk1 * 8;
    const __bf16* gB0 = B + (size_t)(n0 + row0) * KT + k0 + qk0 * 8;
    const __bf16* gB1 = B + (size_t)(n0 + row1) * KT + k0 + qk1 * 8;

    f32x4 acc[4][4] = {};

    const int qa = q ^ ((r16 >> 1) & 3);         // de-swizzle for reads
    const int awOff = (wm * 64 + r16) * 32 + qa * 8;
    const int bwOff = (wn * 64 + r16) * 32 + qa * 8;

    // prologue: stage tile 0 into buffer 0
    gll16(gA0, &As[tid * 8]);
    gll16(gA1, &As[(tid + 256) * 8]);
    gll16(gB0, &Bs[tid * 8]);
    gll16(gB1, &Bs[(tid + 256) * 8]);
    __syncthreads();

    for (int it = 0; it < NIT; ++it) {
        // stage tile it+1 into the other buffer (issue only — no wait).
        // Tail (it==NIT-1) reads past the tile but stays inside mapped ws;
        // those LDS values are never consumed.
        const int ko = (it + 1) * 32;
        const int sb = ((it + 1) & 1) * LBUF;
        gll16(gA0 + ko, &As[sb + tid * 8]);
        gll16(gA1 + ko, &As[sb + (tid + 256) * 8]);
        gll16(gB0 + ko, &Bs[sb + tid * 8]);
        gll16(gB1 + ko, &Bs[sb + (tid + 256) * 8]);

        // compute on buffer it&1
        const int cb = (it & 1) * LBUF;
        const __bf16* Aw = &As[cb + awOff];
        const __bf16* Bw = &Bs[cb + bwOff];
        bf16x8 af[4], bg[4];
#pragma unroll
        for (int mi = 0; mi < 4; ++mi) af[mi] = *(const bf16x8*)(Aw + mi * 512);
#pragma unroll
        for (int ni = 0; ni < 4; ++ni) bg[ni] = *(const bf16x8*)(Bw + ni * 512);
#pragma unroll
        for (int mi = 0; mi < 4; ++mi)
#pragma unroll
            for (int ni = 0; ni < 4; ++ni)
                acc[mi][ni] = __builtin_amdgcn_mfma_f32_16x16x32_bf16(
                    af[mi], bg[ni], acc[mi][ni], 0, 0, 0);

        // single barrier per iter: drains the in-flight DMA (mostly overlapped
        // by the compute above) and protects buffer reuse next iteration.
        __syncthreads();
    }

    // epilogue: C/D layout col=lane&15, row=(lane>>4)*4+reg; bf16 partials
    __bf16* Cb = Cp + (size_t)blockIdx.z * CPE;
#pragma unroll
    for (int mi = 0; mi < 4; ++mi) {
        const int row = m0 + wm * 64 + mi * 16 + q * 4;
#pragma unroll
        for (int ni = 0; ni < 4; ++ni) {
            const int col = n0 + wn * 64 + ni * 16 + r16;
#pragma unroll
            for (int r = 0; r < 4; ++r)
                Cb[(size_t)(row + r) * 512 + col] = (__bf16)acc[mi][ni][r];
        }
    }
}

// ---- kernel 3: sum 8 bf16 partials + LayerNorm, one wave per row ----------
__global__ void ln_kernel(const __bf16* __restrict__ Cp, const float* __restrict__ gamma,
                          const float* __restrict__ beta, float* __restrict__ out) {
    const int tid  = threadIdx.x;
    const int wave = tid >> 6, lane = tid & 63;
    const int row  = blockIdx.x * 4 + wave;
    const size_t base = (size_t)row * 512 + lane * 8;   // 8 contiguous cols/lane

    float v[8] = {};
    float s = 0.f, s2 = 0.f;
#pragma unroll
    for (int z = 0; z < SPLITS; ++z) {
        bf16x8 p = *(const bf16x8*)(Cp + (size_t)z * CPE + base);
#pragma unroll
        for (int j = 0; j < 8; ++j) v[j] += (float)p[j];
    }
#pragma unroll
    for (int j = 0; j < 8; ++j) { s += v[j]; s2 += v[j] * v[j]; }
#pragma unroll
    for (int m = 32; m >= 1; m >>= 1) {
        s  += __shfl_xor(s, m);
        s2 += __shfl_xor(s2, m);
    }
    const float mean = s * (1.0f / 512.0f);
    const float var  = s2 * (1.0f / 512.0f) - mean * mean;
    const float rs   = rsqrtf(var + 1e-5f);
    float4 o0, o1;
    const float4 g0 = *(const float4*)&gamma[lane * 8];
    const float4 g1 = *(const float4*)&gamma[lane * 8 + 4];
    const float4 b0 = *(const float4*)&beta[lane * 8];
    const float4 b1 = *(const float4*)&beta[lane * 8 + 4];
    o0.x = (v[0] - mean) * rs * g0.x + b0.x;
    o0.y = (v[1] - mean) * rs * g0.y + b0.y;
    o0.z = (v[2] - mean) * rs * g0.z + b0.z;
    o0.w = (v[3] - mean) * rs * g0.w + b0.w;
    o1.x = (v[4] - mean) * rs * g1.x + b1.x;
    o1.y = (v[5] - mean) * rs * g1.y + b1.y;
    o1.z = (v[6] - mean) * rs * g1.z + b1.z;
    o1.w = (v[7] - mean) * rs * g1.w + b1.w;
    *(float4*)&out[base]     = o0;
    *(float4*)&out[base + 4] = o1;
}

extern "C" void kernel_launch(void* const* d_in, const int* in_sizes, int n_in,
                              void* d_out, int out_size, void* d_ws, size_t ws_size,
                              hipStream_t stream) {
    const float* x     = (const float*)d_in[0];
    const float* W     = (const float*)d_in[1];
    const float* Wb    = (const float*)d_in[2];
    const float* gamma = (const float*)d_in[3];
    const float* beta  = (const float*)d_in[4];
    float* out = (float*)d_out;

    char* ws = (char*)d_ws;
    __bf16* A  = (__bf16*)ws;                        // 71,303,168 B
    __bf16* Bm = (__bf16*)(ws + 71303168);           //  8,912,896 B
    __bf16* Cp = (__bf16*)(ws + 80216064);           // 33,554,432 B

    prep_AB<<<8192 + 4352, 256, 0, stream>>>(x, W, Wb, A, Bm);
    dim3 g(32, 4, SPLITS);
    gemm_bt<<<g, 256, 0, stream>>>(A, Bm, Cp);
    ln_kernel<<<1024, 256, 0, stream>>>(Cp, gamma, beta, out);
}